// Round 1
// baseline (79.786 us; speedup 1.0000x reference)
//
#include <hip/hip_runtime.h>

// ProtoLayer: out[t][q][w] = -sum_c (query[t][q][c] - mean_s support[t][w*S+s][c])^2
// T=4, WAY=16, SHOT=8, QUERY=256 (=> 4096 queries/t), C=256. fp32 in/out.
// support_target is unused by the reference (prototype = reshape-mean).
//
// SINGLE fused kernel — the previous 2-kernel version staged prototypes through
// d_ws, and the harness re-poisons the ENTIRE 256 MiB workspace inside the timed
// loop when ws is used: rocprof showed the top-5 dispatches were all
// fillBufferAligned @ ~43 us, WRITE_SIZE = 256 MiB, ~87 us of fill vs ~7 us of
// actual kernel work. Recomputing the 16 prototypes per block from support
// (512 KB, L2-resident) costs ~2 us aggregate and eliminates the ws poison.
//
// Block = 32 queries x 16 ways, 128 threads; thread = 2 queries x 2 ways tile
// -> 4 ds_read_b128 per c4-step (DS-pipe floor ~5 us).
// LDS pitch 260 floats => broadcast reads are 2-way bank aliased (free, m136).

constexpr int T_    = 4;
constexpr int WAY   = 16;
constexpr int SHOT  = 8;
constexpr int C     = 256;
constexpr int WQ    = 4096;            // WAY*QUERY queries per t
constexpr int C4    = C / 4;           // 64 float4 per row
constexpr int PITCH = 260;             // LDS row pitch in floats

__global__ __launch_bounds__(128) void fused_kernel(
    const float* __restrict__ query,    // (T, WQ, C)
    const float* __restrict__ support,  // (T, WAY*SHOT, C)
    float* __restrict__ out)            // (T, WQ, WAY)
{
    __shared__ float ps[WAY * PITCH];   // 16.6 KB
    __shared__ float qs[32  * PITCH];   // 33.3 KB   (total ~50 KB -> 3 blocks/CU cap)

    const int tid = threadIdx.x;
    const int t   = blockIdx.x >> 7;            // 128 blocks per t
    const int qb  = (blockIdx.x & 127) * 32;

    // ---- prototypes: mean over shots, computed per block straight from support.
    // 1024 float4 outputs / 128 thr = 8 each; inner 8-shot sum reads are
    // coalesced per half-wave (consecutive c4 within one support row).
    {
        const float4* base = (const float4*)(support + (size_t)t * (WAY * SHOT * C));
        #pragma unroll
        for (int i = 0; i < 8; ++i) {
            int idx = tid + i * 128;            // [0,1024)
            int w = idx >> 6, c4 = idx & 63;
            const float4* row = base + (w * SHOT) * C4 + c4;
            float sx = 0.f, sy = 0.f, sz = 0.f, sw = 0.f;
            #pragma unroll
            for (int sh = 0; sh < SHOT; ++sh) {
                float4 v = row[sh * C4];
                sx += v.x; sy += v.y; sz += v.z; sw += v.w;
            }
            *(float4*)&ps[w * PITCH + c4 * 4] =
                make_float4(sx * 0.125f, sy * 0.125f, sz * 0.125f, sw * 0.125f);
        }
    }

    // ---- stage query tile: 32 rows x 64 float4 = 2048 / 128 thr = 16 each ----
    {
        const float4* src = (const float4*)(query + ((size_t)t * WQ + qb) * C);
        #pragma unroll
        for (int i = 0; i < 16; ++i) {
            int idx = tid + i * 128;            // [0,2048)
            int q = idx >> 6, c4 = idx & 63;
            float4 v = src[idx];
            *(float4*)&qs[q * PITCH + c4 * 4] = v;
        }
    }
    __syncthreads();

    const int ql = tid >> 3;            // [0,16): queries 2ql, 2ql+1 (block-local)
    const int wg = (tid & 7) * 2;       // ways wg, wg+1

    const float* q0 = &qs[(2 * ql + 0) * PITCH];
    const float* q1 = &qs[(2 * ql + 1) * PITCH];
    const float* p0 = &ps[(wg + 0) * PITCH];
    const float* p1 = &ps[(wg + 1) * PITCH];

    float a00 = 0.f, a01 = 0.f, a10 = 0.f, a11 = 0.f;
    #pragma unroll 8
    for (int c = 0; c < C; c += 4) {
        float4 qa = *(const float4*)(q0 + c);
        float4 qv = *(const float4*)(q1 + c);
        float4 pa = *(const float4*)(p0 + c);
        float4 pb = *(const float4*)(p1 + c);

        float d;
        d = qa.x - pa.x; a00 += d * d;
        d = qa.y - pa.y; a00 += d * d;
        d = qa.z - pa.z; a00 += d * d;
        d = qa.w - pa.w; a00 += d * d;

        d = qa.x - pb.x; a01 += d * d;
        d = qa.y - pb.y; a01 += d * d;
        d = qa.z - pb.z; a01 += d * d;
        d = qa.w - pb.w; a01 += d * d;

        d = qv.x - pa.x; a10 += d * d;
        d = qv.y - pa.y; a10 += d * d;
        d = qv.z - pa.z; a10 += d * d;
        d = qv.w - pa.w; a10 += d * d;

        d = qv.x - pb.x; a11 += d * d;
        d = qv.y - pb.y; a11 += d * d;
        d = qv.z - pb.z; a11 += d * d;
        d = qv.w - pb.w; a11 += d * d;
    }

    // queries are consecutive, ways adjacent -> two float2 stores, 64B-chunk coalesced
    float* ob = out + (((size_t)t * WQ + qb + 2 * ql) * WAY + wg);
    *(float2*)ob         = make_float2(-a00, -a01);
    *(float2*)(ob + WAY) = make_float2(-a10, -a11);
}

extern "C" void kernel_launch(void* const* d_in, const int* in_sizes, int n_in,
                              void* d_out, int out_size, void* d_ws, size_t ws_size,
                              hipStream_t stream) {
    const float* query   = (const float*)d_in[0];
    const float* support = (const float*)d_in[1];
    // d_in[2] (support_target) unused: reference ignores labels (plain reshape-mean).
    float* out = (float*)d_out;
    (void)d_ws; (void)ws_size;          // deliberately untouched: avoids 256 MiB re-poison fills

    fused_kernel<<<dim3(T_ * 128), 128, 0, stream>>>(query, support, out);
}